// Round 5
// baseline (2165.288 us; speedup 1.0000x reference)
//
#include <hip/hip_runtime.h>

#define EPSBN 2e-5f

// ---------------------------------------------------------------------------
// Padded x staging
// ---------------------------------------------------------------------------
constexpr int XPADL = 9984;
constexpr int XPADR = 14336;
constexpr int PROW = XPADL + 32768 + XPADR;  // 57088

__global__ __launch_bounds__(256) void pad_x_kernel(const float* __restrict__ x,
                                                    float* __restrict__ xp) {
  int i = blockIdx.x * 256 + threadIdx.x;
  if (i >= 8 * PROW) return;
  int b = i / PROW;
  int pos = i - b * PROW - XPADL;
  xp[i] = (pos >= 0 && pos < 32768) ? x[b * 32768 + pos] : 0.f;
}

// ---------------------------------------------------------------------------
// Lift conv K=79 (dilation 2^S, scale 1/2^S) + pool4 + BN-stats, templated S.
// ---------------------------------------------------------------------------
template <int S>
__global__ __launch_bounds__(256) void lift_pool2_kernel(
    const float* __restrict__ xp, const float* __restrict__ w1,
    float* __restrict__ y1, float* __restrict__ st) {
  constexpr int d = 1 << S;
  constexpr float inv = 1.f / (float)d;
  const int tile = blockIdx.x;
  const int c = blockIdx.y;
  const int b = blockIdx.z;
  const int l0 = tile * 4096;
  const int t = threadIdx.x;
  const int q = t & (d - 1);
  const int j = t >> S;
  const int base = l0 + q + ((j * 16) << S);
  const float* xrow = xp + b * PROW + XPADL;
  const float* wr = w1 + c * 79;

  float acc[16], win[16];
#pragma unroll
  for (int r = 0; r < 16; ++r) acc[r] = 0.f;
  int idx = base - 39 * d;
#pragma unroll
  for (int i = 0; i < 16; ++i) {
    win[i] = xrow[idx];
    idx += d;
  }
#pragma unroll
  for (int ko = 0; ko < 5; ++ko) {
#pragma unroll
    for (int kj = 0; kj < 16; ++kj) {
      const int k = ko * 16 + kj;
      const float wk = (k < 79) ? wr[k] : 0.f;
#pragma unroll
      for (int r = 0; r < 16; ++r)
        acc[r] = fmaf(wk, win[(kj + r) & 15], acc[r]);
      win[kj] = xrow[idx];
      idx += d;
    }
  }

  float ssum = 0.f, ssq = 0.f;
  float* yrow = y1 + (((size_t)b * 51 + c) * 9 + S) * 8192 + (l0 >> 2);
  if constexpr (S == 0) {
#pragma unroll
    for (int m = 0; m < 4; ++m) {
      float v = fmaxf(fmaxf(acc[4 * m], acc[4 * m + 1]),
                      fmaxf(acc[4 * m + 2], acc[4 * m + 3]));
      yrow[4 * t + m] = v;
      ssum += v;
      ssq += v * v;
    }
  } else if constexpr (S == 1) {
#pragma unroll
    for (int m = 0; m < 8; ++m) {
      float u = fmaxf(acc[2 * m], acc[2 * m + 1]);
      u = fmaxf(u, __shfl_xor(u, 1));
      if ((t & 1) == 0) {
        float v = u * inv;
        yrow[8 * j + m] = v;
        ssum += v;
        ssq += v * v;
      }
    }
  } else {
#pragma unroll
    for (int r = 0; r < 16; ++r) {
      float u = fmaxf(acc[r], __shfl_xor(acc[r], 1));
      u = fmaxf(u, __shfl_xor(u, 2));
      if ((t & 3) == 0) {
        float v = u * inv;
        yrow[(q >> 2) + ((j * 16 + r) << (S - 2))] = v;
        ssum += v;
        ssq += v * v;
      }
    }
  }
#pragma unroll
  for (int off = 32; off > 0; off >>= 1) {
    ssum += __shfl_down(ssum, off);
    ssq += __shfl_down(ssq, off);
  }
  __shared__ float rs[4], rq[4];
  const int wid = t >> 6;
  if ((t & 63) == 0) {
    rs[wid] = ssum;
    rq[wid] = ssq;
  }
  __syncthreads();
  if (t == 0) {
    atomicAdd(&st[c], rs[0] + rs[1] + rs[2] + rs[3]);
    atomicAdd(&st[512 + c], rq[0] + rq[1] + rq[2] + rq[3]);
  }
}

// ---------------------------------------------------------------------------
// BN(train) + ReLU + pool4
// ---------------------------------------------------------------------------
__global__ __launch_bounds__(256) void bnrelu_pool_kernel(
    const float* __restrict__ Y, const float* __restrict__ st,
    const float* __restrict__ g, const float* __restrict__ bb,
    float* __restrict__ Z, int C, int H, int Lin, float invN,
    unsigned int total) {
  unsigned int idx = blockIdx.x * 256u + threadIdx.x;
  if (idx >= total) return;
  const unsigned int Lo = (unsigned int)(Lin >> 2);
  unsigned int lo = idx % Lo;
  unsigned int r1 = idx / Lo;
  unsigned int h = r1 % (unsigned int)H;
  unsigned int r2 = r1 / (unsigned int)H;
  unsigned int c = r2 % (unsigned int)C;
  unsigned int b = r2 / (unsigned int)C;
  float m = st[c] * invN;
  float v = st[512 + c] * invN - m * m;
  float sc = g[c] * rsqrtf(v + EPSBN);
  float bi = bb[c] - m * sc;
  const float* p = Y + (((size_t)b * C + c) * H + h) * Lin + 4u * lo;
  float a0 = p[0] * sc + bi, a1 = p[1] * sc + bi;
  float a2 = p[2] * sc + bi, a3 = p[3] * sc + bi;
  float r = fmaxf(fmaxf(a0, a1), fmaxf(a2, a3));
  Z[idx] = fmaxf(r, 0.f);
}

// ---------------------------------------------------------------------------
// BN(train) + ReLU, elementwise
// ---------------------------------------------------------------------------
__global__ __launch_bounds__(256) void bnrelu_kernel(
    const float* __restrict__ Y, const float* __restrict__ st,
    const float* __restrict__ g, const float* __restrict__ bb,
    float* __restrict__ A, int C, int HL, float invN, unsigned int total) {
  unsigned int idx = blockIdx.x * 256u + threadIdx.x;
  if (idx >= total) return;
  unsigned int c = (idx / (unsigned int)HL) % (unsigned int)C;
  float m = st[c] * invN;
  float v = st[512 + c] * invN - m * m;
  float sc = g[c] * rsqrtf(v + EPSBN);
  float bi = bb[c] - m * sc;
  A[idx] = fmaxf(fmaf(Y[idx], sc, bi), 0.f);
}

// ---------------------------------------------------------------------------
// gg_big2: pipelined, conflict-free GConvGG for the large stages.
// 256 thr = 4 waves; wave -> 8 consecutive co (scalar weights); lane -> JT
// l-positions at stride 64 (conflict-free LDS).  Register-prefetch pipeline:
// chunk k+1's raw global loads issue before the barrier and are consumed
// (bn+relu+1/d transform + ds_write) after chunk k's compute.
// CHUNK must divide Ci.  LBLK = 64*JT.
// ---------------------------------------------------------------------------
template <int NK, int CHUNK, int MAXD, int JT>
__global__ __launch_bounds__(256) void gg_big2_kernel(
    const float* __restrict__ X, const float* __restrict__ W,
    const float* __restrict__ stIn, const float* __restrict__ gIn,
    const float* __restrict__ bIn, float invNIn, float* __restrict__ Y,
    float* __restrict__ stOut, int Ci, int Co, int Hin, int L) {
  constexpr int LBLK = 64 * JT;
  constexpr int PITCH = LBLK + 2 * MAXD;
  constexpr int ROWS = CHUNK * NK;
  constexpr int REPS = (PITCH + 255) / 256;

  const int lChunks = L / LBLK;
  const int lc = blockIdx.x % lChunks;
  const int cochunk = blockIdx.x / lChunks;
  const int s = blockIdx.y;
  const int b = blockIdx.z;
  const int Hout = Hin - NK + 1;
  const int l0 = lc * LBLK;
  const int tid = threadIdx.x;
  const int lane = tid & 63;
  const int wv = __builtin_amdgcn_readfirstlane(tid >> 6);
  const int coBase = cochunk * 32 + wv * 8;

  __shared__ float lds[ROWS * PITCH];
  __shared__ float insc[416], inbi[416];

  for (int c = tid; c < Ci; c += 256) {
    float sc = 1.f, bi = 0.f;
    if (stIn) {
      float m = stIn[c] * invNIn;
      float v = stIn[512 + c] * invNIn - m * m;
      sc = gIn[c] * rsqrtf(v + EPSBN);
      bi = bIn[c] - m * sc;
    }
    insc[c] = sc;
    inbi[c] = bi;
  }
  __syncthreads();

  const bool interior = (l0 >= MAXD) && (l0 + PITCH <= L);

  float pre[ROWS][REPS];

  auto loadChunk = [&](int c0) {
#pragma unroll
    for (int r = 0; r < ROWS; ++r) {
      const int i = r % NK;
      const int ci = c0 * CHUNK + r / NK;
      const int dd = 1 << (s + i);
      const float* src = X + (((size_t)b * Ci + ci) * Hin + (s + i)) * L;
#pragma unroll
      for (int rep = 0; rep < REPS; ++rep) {
        const int p = tid + rep * 256;
        if (p < PITCH) {
          int pos = l0 - dd + p;
          if (!interior) pos = min(max(pos, 0), L - 1);
          pre[r][rep] = src[pos];
        }
      }
    }
  };

  auto writeChunk = [&](int c0) {
#pragma unroll
    for (int r = 0; r < ROWS; ++r) {
      const int i = r % NK;
      const int ci = c0 * CHUNK + r / NK;
      const int dd = 1 << (s + i);
      const float inv = __uint_as_float((unsigned)(127 - (s + i)) << 23);
      const float sc = insc[ci], bi = inbi[ci];
#pragma unroll
      for (int rep = 0; rep < REPS; ++rep) {
        const int p = tid + rep * 256;
        if (p < PITCH) {
          float a = fmaxf(fmaf(pre[r][rep], sc, bi), 0.f) * inv;
          if (!interior) {
            int pos = l0 - dd + p;
            if (pos < 0 || pos >= L) a = 0.f;
          }
          lds[r * PITCH + p] = a;
        }
      }
    }
  };

  float acc[8][JT];
#pragma unroll
  for (int r = 0; r < 8; ++r)
#pragma unroll
    for (int j = 0; j < JT; ++j) acc[r][j] = 0.f;

  const int nChunks = Ci / CHUNK;
  loadChunk(0);
  for (int c0 = 0; c0 < nChunks; ++c0) {
    writeChunk(c0);
    if (c0 + 1 < nChunks) loadChunk(c0 + 1);
    __syncthreads();
    for (int cc = 0; cc < CHUNK; ++cc) {
      const int ci = c0 * CHUNK + cc;
#pragma unroll
      for (int i = 0; i < NK; ++i) {
        const int dd = 1 << (s + i);
        const float* row = lds + (cc * NK + i) * PITCH + lane;
        float x0[JT], x1[JT], x2[JT];
#pragma unroll
        for (int j = 0; j < JT; ++j) {
          x0[j] = row[64 * j];
          x1[j] = row[64 * j + dd];
          x2[j] = row[64 * j + 2 * dd];
        }
#pragma unroll
        for (int r = 0; r < 8; ++r) {
          const int co = min(coBase + r, Co - 1);
          const float* w3 = W + (((size_t)co * Ci + ci) * NK + i) * 3;
          const float w0 = w3[0], w1 = w3[1], w2 = w3[2];
#pragma unroll
          for (int j = 0; j < JT; ++j)
            acc[r][j] =
                fmaf(w0, x0[j], fmaf(w1, x1[j], fmaf(w2, x2[j], acc[r][j])));
        }
      }
    }
    __syncthreads();
  }

#pragma unroll
  for (int r = 0; r < 8; ++r) {
    const int co = coBase + r;
    if (co < Co) {
      float* yp = Y + (((size_t)b * Co + co) * Hout + s) * L + l0 + lane;
      float s1 = 0.f, s2 = 0.f;
#pragma unroll
      for (int j = 0; j < JT; ++j) {
        yp[64 * j] = acc[r][j];
        s1 += acc[r][j];
        s2 += acc[r][j] * acc[r][j];
      }
      if (stOut) {
#pragma unroll
        for (int off = 32; off > 0; off >>= 1) {
          s1 += __shfl_xor(s1, off);
          s2 += __shfl_xor(s2, off);
        }
        if (lane == 0) {
          atomicAdd(&stOut[co], s1);
          atomicAdd(&stOut[512 + co], s2);
        }
      }
    }
  }
}

// ---------------------------------------------------------------------------
// gg_tail: no-LDS GConvGG for small stages (input pre-activated)
// ---------------------------------------------------------------------------
template <int NK, int L, int COSUB>
__global__ __launch_bounds__(256) void gg_tail_kernel(
    const float* __restrict__ X, const float* __restrict__ W,
    float* __restrict__ Y, float* __restrict__ stOut, int Ci, int Co,
    int Hin) {
  const int l = threadIdx.x % L;
  const int cs = threadIdx.x / L;
  const int co = blockIdx.x * COSUB + cs;
  const int s = blockIdx.y;
  const int b = blockIdx.z;
  const int Hout = Hin - NK + 1;

  float acc[NK];
#pragma unroll
  for (int i = 0; i < NK; ++i) acc[i] = 0.f;

  const float* wbase = W + (size_t)co * Ci * NK * 3;
  const float* xbase = X + ((size_t)b * Ci * Hin + s) * L;

  for (int ci = 0; ci < Ci; ++ci) {
    const float* wp = wbase + ci * (NK * 3);
    const float* xr = xbase + ci * (Hin * L);
#pragma unroll
    for (int i = 0; i < NK; ++i) {
      const int d = 1 << (s + i);
      const float* row = xr + i * L;
      float xm = (l >= d) ? row[l - d] : 0.f;
      float xc = row[l];
      float xp = (l + d < L) ? row[l + d] : 0.f;
      acc[i] = fmaf(wp[3 * i], xm,
                    fmaf(wp[3 * i + 1], xc, fmaf(wp[3 * i + 2], xp, acc[i])));
    }
  }
  float out = 0.f;
#pragma unroll
  for (int i = 0; i < NK; ++i) {
    float invd = __uint_as_float((unsigned)(127 - (s + i)) << 23);
    out = fmaf(acc[i], invd, out);
  }
  Y[(((size_t)b * Co + co) * Hout + s) * L + l] = out;

  float s1 = out, s2 = out * out;
  constexpr int RED = (L < 64) ? L : 64;
#pragma unroll
  for (int off = RED / 2; off > 0; off >>= 1) {
    s1 += __shfl_xor(s1, off);
    s2 += __shfl_xor(s2, off);
  }
  if ((threadIdx.x & (RED - 1)) == 0) {
    atomicAdd(&stOut[co], s1);
    atomicAdd(&stOut[512 + co], s2);
  }
}

// ---------------------------------------------------------------------------
// Final: bn10+relu, mean over L, classifier
// ---------------------------------------------------------------------------
__global__ __launch_bounds__(256) void final_kernel(
    const float* __restrict__ Y, const float* __restrict__ st,
    const float* __restrict__ g, const float* __restrict__ bb,
    const float* __restrict__ w11, float* __restrict__ out) {
  const int b = blockIdx.x;
  const int tid = threadIdx.x;
  __shared__ float tch[408];
  for (int c = tid; c < 408; c += 256) {
    float m = st[c] * (1.f / 256.f);
    float v = st[512 + c] * (1.f / 256.f) - m * m;
    float sc = g[c] * rsqrtf(v + EPSBN);
    float bi = bb[c] - m * sc;
    const float* p = Y + ((size_t)b * 408 + c) * 32;
    float ssum = 0.f;
#pragma unroll
    for (int l = 0; l < 32; ++l) ssum += fmaxf(p[l] * sc + bi, 0.f);
    tch[c] = ssum * (1.f / 32.f);
  }
  __syncthreads();
  if (tid < 10) {
    float ssum = 0.f;
    for (int c = 0; c < 408; ++c) ssum += w11[tid * 408 + c] * tch[c];
    out[b * 10 + tid] = ssum;
  }
}

// ---------------------------------------------------------------------------
extern "C" void kernel_launch(void* const* d_in, const int* in_sizes, int n_in,
                              void* d_out, int out_size, void* d_ws,
                              size_t ws_size, hipStream_t stream) {
  const float* x = (const float*)d_in[0];
  const float* w1 = (const float*)d_in[1];
  const float* w2 = (const float*)d_in[2];
  const float* w3 = (const float*)d_in[3];
  const float* w4 = (const float*)d_in[4];
  const float* w5 = (const float*)d_in[5];
  const float* w6 = (const float*)d_in[6];
  const float* w7 = (const float*)d_in[7];
  const float* w8 = (const float*)d_in[8];
  const float* w9 = (const float*)d_in[9];
  const float* w10 = (const float*)d_in[10];
  const float* w11 = (const float*)d_in[11];
  const float* gg[11];
  const float* bbv[11];
  for (int i = 1; i <= 10; ++i) {
    gg[i] = (const float*)d_in[12 + 2 * (i - 1)];
    bbv[i] = (const float*)d_in[12 + 2 * (i - 1) + 1];
  }

  float* ws = (float*)d_ws;
  const size_t AR0 = 0;
  const size_t AR1 = 30081024;
  const size_t STATS = 37601280;
  float* y1 = ws + AR0;
  float* xpad = ws + AR1;
  float* z1 = ws + AR1;
  float* y2 = ws + AR0;
  float* y3 = ws + AR0 + 5849088;
  float* z3 = ws + AR1;
  float* y4 = ws + AR0;
  float* y5 = ws + AR0 + 2088960;
  float* z5 = ws + AR1;
  float* a6 = ws + AR1 + 522240;
  float* a7 = ws + AR1 + 1148928;
  float* z8 = ws + AR1;
  float* a9 = ws + AR1 + 1775616;
  float* y6 = ws + AR0;
  float* y7 = ws + AR0 + 626688;
  float* y8 = ws + AR0 + 1253376;
  float* y9 = ws + AR0;
  float* y10 = ws + AR0 + 104448;
  float* st[11];
  for (int i = 1; i <= 10; ++i) st[i] = ws + STATS + (size_t)(i - 1) * 1024;

  hipMemsetAsync((void*)(ws + STATS), 0, 10 * 1024 * sizeof(float), stream);

  // ---- pad + lift (stats1 fused)
  pad_x_kernel<<<(8 * PROW + 255) / 256, 256, 0, stream>>>(x, xpad);
  {
    dim3 g(8, 51, 8);
    lift_pool2_kernel<0><<<g, 256, 0, stream>>>(xpad, w1, y1, st[1]);
    lift_pool2_kernel<1><<<g, 256, 0, stream>>>(xpad, w1, y1, st[1]);
    lift_pool2_kernel<2><<<g, 256, 0, stream>>>(xpad, w1, y1, st[1]);
    lift_pool2_kernel<3><<<g, 256, 0, stream>>>(xpad, w1, y1, st[1]);
    lift_pool2_kernel<4><<<g, 256, 0, stream>>>(xpad, w1, y1, st[1]);
    lift_pool2_kernel<5><<<g, 256, 0, stream>>>(xpad, w1, y1, st[1]);
    lift_pool2_kernel<6><<<g, 256, 0, stream>>>(xpad, w1, y1, st[1]);
    lift_pool2_kernel<7><<<g, 256, 0, stream>>>(xpad, w1, y1, st[1]);
    lift_pool2_kernel<8><<<g, 256, 0, stream>>>(xpad, w1, y1, st[1]);
  }
  {
    unsigned int tot = 8u * 51 * 9 * 2048;
    bnrelu_pool_kernel<<<(tot + 255) / 256, 256, 0, stream>>>(
        y1, st[1], gg[1], bbv[1], z1, 51, 9, 8192, 1.f / 589824.f, tot);
  }
  // ---- gg2: 51->51, H 9->7, L=2048 (stats fused)   [8 lc x 2 cochunk]
  gg_big2_kernel<3, 3, 256, 4><<<dim3(16, 7, 8), 256, 0, stream>>>(
      z1, w2, nullptr, nullptr, nullptr, 0.f, y2, st[2], 51, 51, 9, 2048);
  // ---- gg3: 51->51, H7, L=2048 (bn2 on load, stats fused)
  gg_big2_kernel<1, 17, 64, 4><<<dim3(16, 7, 8), 256, 0, stream>>>(
      y2, w3, st[2], gg[2], bbv[2], 1.f / 114688.f, y3, st[3], 51, 51, 7,
      2048);
  {
    unsigned int tot = 8u * 51 * 7 * 512;
    bnrelu_pool_kernel<<<(tot + 255) / 256, 256, 0, stream>>>(
        y3, st[3], gg[3], bbv[3], z3, 51, 7, 2048, 1.f / 114688.f, tot);
  }
  // ---- gg4: 51->102, H 7->5, L=512   [4 lc x 4 cochunk]
  gg_big2_kernel<3, 3, 64, 2><<<dim3(16, 5, 8), 256, 0, stream>>>(
      z3, w4, nullptr, nullptr, nullptr, 0.f, y4, st[4], 51, 102, 7, 512);
  // ---- gg5: 102->102, H5, L=512
  gg_big2_kernel<1, 17, 16, 2><<<dim3(16, 5, 8), 256, 0, stream>>>(
      y4, w5, st[4], gg[4], bbv[4], 1.f / 20480.f, y5, st[5], 102, 102, 5,
      512);
  {
    unsigned int tot = 8u * 102 * 5 * 128;
    bnrelu_pool_kernel<<<(tot + 255) / 256, 256, 0, stream>>>(
        y5, st[5], gg[5], bbv[5], z5, 102, 5, 512, 1.f / 20480.f, tot);
  }
  // ---- gg6: 102->204, H 5->3, L=128
  gg_tail_kernel<3, 128, 2><<<dim3(102, 3, 8), 256, 0, stream>>>(
      z5, w6, y6, st[6], 102, 204, 5);
  {
    unsigned int tot = 8u * 204 * 3 * 128;
    bnrelu_kernel<<<(tot + 255) / 256, 256, 0, stream>>>(
        y6, st[6], gg[6], bbv[6], a6, 204, 3 * 128, 1.f / 3072.f, tot);
  }
  // ---- gg7: 204->204, H3, L=128
  gg_tail_kernel<1, 128, 2><<<dim3(102, 3, 8), 256, 0, stream>>>(
      a6, w7, y7, st[7], 204, 204, 3);
  {
    unsigned int tot = 8u * 204 * 3 * 128;
    bnrelu_kernel<<<(tot + 255) / 256, 256, 0, stream>>>(
        y7, st[7], gg[7], bbv[7], a7, 204, 3 * 128, 1.f / 3072.f, tot);
  }
  // ---- gg8: 204->204, H3, L=128
  gg_tail_kernel<1, 128, 2><<<dim3(102, 3, 8), 256, 0, stream>>>(
      a7, w8, y8, st[8], 204, 204, 3);
  {
    unsigned int tot = 8u * 204 * 3 * 32;
    bnrelu_pool_kernel<<<(tot + 255) / 256, 256, 0, stream>>>(
        y8, st[8], gg[8], bbv[8], z8, 204, 3, 128, 1.f / 3072.f, tot);
  }
  // ---- gg9: 204->408, H 3->1, L=32
  gg_tail_kernel<3, 32, 8><<<dim3(51, 1, 8), 256, 0, stream>>>(
      z8, w9, y9, st[9], 204, 408, 3);
  {
    unsigned int tot = 8u * 408 * 32;
    bnrelu_kernel<<<(tot + 255) / 256, 256, 0, stream>>>(
        y9, st[9], gg[9], bbv[9], a9, 408, 32, 1.f / 256.f, tot);
  }
  // ---- gg10: 408->408, H1, L=32
  gg_tail_kernel<1, 32, 8><<<dim3(51, 1, 8), 256, 0, stream>>>(
      a9, w10, y10, st[10], 408, 408, 1);
  // ---- final
  final_kernel<<<dim3(8), 256, 0, stream>>>(y10, st[10], gg[10], bbv[10], w11,
                                            (float*)d_out);
}

// Round 6
// 2009.900 us; speedup vs baseline: 1.0773x; 1.0773x over previous
//
#include <hip/hip_runtime.h>

#define EPSBN 2e-5f

// ---------------------------------------------------------------------------
// Padded x staging
// ---------------------------------------------------------------------------
constexpr int XPADL = 9984;
constexpr int XPADR = 14336;
constexpr int PROW = XPADL + 32768 + XPADR;  // 57088

__global__ __launch_bounds__(256) void pad_x_kernel(const float* __restrict__ x,
                                                    float* __restrict__ xp) {
  int i = blockIdx.x * 256 + threadIdx.x;
  if (i >= 8 * PROW) return;
  int b = i / PROW;
  int pos = i - b * PROW - XPADL;
  xp[i] = (pos >= 0 && pos < 32768) ? x[b * 32768 + pos] : 0.f;
}

// ---------------------------------------------------------------------------
// Lift conv K=79 (dilation 2^S, scale 1/2^S) + pool4 + BN-stats, templated S.
// ---------------------------------------------------------------------------
template <int S>
__global__ __launch_bounds__(256) void lift_pool2_kernel(
    const float* __restrict__ xp, const float* __restrict__ w1,
    float* __restrict__ y1, float* __restrict__ st) {
  constexpr int d = 1 << S;
  constexpr float inv = 1.f / (float)d;
  const int tile = blockIdx.x;
  const int c = blockIdx.y;
  const int b = blockIdx.z;
  const int l0 = tile * 4096;
  const int t = threadIdx.x;
  const int q = t & (d - 1);
  const int j = t >> S;
  const int base = l0 + q + ((j * 16) << S);
  const float* xrow = xp + b * PROW + XPADL;
  const float* wr = w1 + c * 79;

  float acc[16], win[16];
#pragma unroll
  for (int r = 0; r < 16; ++r) acc[r] = 0.f;
  int idx = base - 39 * d;
#pragma unroll
  for (int i = 0; i < 16; ++i) {
    win[i] = xrow[idx];
    idx += d;
  }
#pragma unroll
  for (int ko = 0; ko < 5; ++ko) {
#pragma unroll
    for (int kj = 0; kj < 16; ++kj) {
      const int k = ko * 16 + kj;
      const float wk = (k < 79) ? wr[k] : 0.f;
#pragma unroll
      for (int r = 0; r < 16; ++r)
        acc[r] = fmaf(wk, win[(kj + r) & 15], acc[r]);
      win[kj] = xrow[idx];
      idx += d;
    }
  }

  float ssum = 0.f, ssq = 0.f;
  float* yrow = y1 + (((size_t)b * 51 + c) * 9 + S) * 8192 + (l0 >> 2);
  if constexpr (S == 0) {
#pragma unroll
    for (int m = 0; m < 4; ++m) {
      float v = fmaxf(fmaxf(acc[4 * m], acc[4 * m + 1]),
                      fmaxf(acc[4 * m + 2], acc[4 * m + 3]));
      yrow[4 * t + m] = v;
      ssum += v;
      ssq += v * v;
    }
  } else if constexpr (S == 1) {
#pragma unroll
    for (int m = 0; m < 8; ++m) {
      float u = fmaxf(acc[2 * m], acc[2 * m + 1]);
      u = fmaxf(u, __shfl_xor(u, 1));
      if ((t & 1) == 0) {
        float v = u * inv;
        yrow[8 * j + m] = v;
        ssum += v;
        ssq += v * v;
      }
    }
  } else {
#pragma unroll
    for (int r = 0; r < 16; ++r) {
      float u = fmaxf(acc[r], __shfl_xor(acc[r], 1));
      u = fmaxf(u, __shfl_xor(u, 2));
      if ((t & 3) == 0) {
        float v = u * inv;
        yrow[(q >> 2) + ((j * 16 + r) << (S - 2))] = v;
        ssum += v;
        ssq += v * v;
      }
    }
  }
#pragma unroll
  for (int off = 32; off > 0; off >>= 1) {
    ssum += __shfl_down(ssum, off);
    ssq += __shfl_down(ssq, off);
  }
  __shared__ float rs[4], rq[4];
  const int wid = t >> 6;
  if ((t & 63) == 0) {
    rs[wid] = ssum;
    rq[wid] = ssq;
  }
  __syncthreads();
  if (t == 0) {
    atomicAdd(&st[c], rs[0] + rs[1] + rs[2] + rs[3]);
    atomicAdd(&st[512 + c], rq[0] + rq[1] + rq[2] + rq[3]);
  }
}

// ---------------------------------------------------------------------------
// Per-channel sum/sumsq over [B,C,HL]; grid (C,B)
// ---------------------------------------------------------------------------
__global__ __launch_bounds__(256) void stats_kernel(
    const float* __restrict__ Y, float* __restrict__ st, int C, int HL) {
  const int c = blockIdx.x, b = blockIdx.y;
  const float* p = Y + ((size_t)b * C + c) * HL;
  float s = 0.f, q = 0.f;
  for (int i = threadIdx.x; i < HL; i += 256) {
    float v = p[i];
    s += v;
    q += v * v;
  }
#pragma unroll
  for (int off = 32; off > 0; off >>= 1) {
    s += __shfl_down(s, off, 64);
    q += __shfl_down(q, off, 64);
  }
  __shared__ float ls[4], lq[4];
  const int wid = threadIdx.x >> 6, lane = threadIdx.x & 63;
  if (lane == 0) { ls[wid] = s; lq[wid] = q; }
  __syncthreads();
  if (threadIdx.x == 0) {
    atomicAdd(&st[c], ls[0] + ls[1] + ls[2] + ls[3]);
    atomicAdd(&st[512 + c], lq[0] + lq[1] + lq[2] + lq[3]);
  }
}

// ---------------------------------------------------------------------------
// BN(train) + ReLU + pool4
// ---------------------------------------------------------------------------
__global__ __launch_bounds__(256) void bnrelu_pool_kernel(
    const float* __restrict__ Y, const float* __restrict__ st,
    const float* __restrict__ g, const float* __restrict__ bb,
    float* __restrict__ Z, int C, int H, int Lin, float invN,
    unsigned int total) {
  unsigned int idx = blockIdx.x * 256u + threadIdx.x;
  if (idx >= total) return;
  const unsigned int Lo = (unsigned int)(Lin >> 2);
  unsigned int lo = idx % Lo;
  unsigned int r1 = idx / Lo;
  unsigned int h = r1 % (unsigned int)H;
  unsigned int r2 = r1 / (unsigned int)H;
  unsigned int c = r2 % (unsigned int)C;
  unsigned int b = r2 / (unsigned int)C;
  float m = st[c] * invN;
  float v = st[512 + c] * invN - m * m;
  float sc = g[c] * rsqrtf(v + EPSBN);
  float bi = bb[c] - m * sc;
  const float* p = Y + (((size_t)b * C + c) * H + h) * Lin + 4u * lo;
  float a0 = p[0] * sc + bi, a1 = p[1] * sc + bi;
  float a2 = p[2] * sc + bi, a3 = p[3] * sc + bi;
  float r = fmaxf(fmaxf(a0, a1), fmaxf(a2, a3));
  Z[idx] = fmaxf(r, 0.f);
}

// ---------------------------------------------------------------------------
// BN(train) + ReLU, elementwise
// ---------------------------------------------------------------------------
__global__ __launch_bounds__(256) void bnrelu_kernel(
    const float* __restrict__ Y, const float* __restrict__ st,
    const float* __restrict__ g, const float* __restrict__ bb,
    float* __restrict__ A, int C, int HL, float invN, unsigned int total) {
  unsigned int idx = blockIdx.x * 256u + threadIdx.x;
  if (idx >= total) return;
  unsigned int c = (idx / (unsigned int)HL) % (unsigned int)C;
  float m = st[c] * invN;
  float v = st[512 + c] * invN - m * m;
  float sc = g[c] * rsqrtf(v + EPSBN);
  float bi = bb[c] - m * sc;
  A[idx] = fmaxf(fmaf(Y[idx], sc, bi), 0.f);
}

// ---------------------------------------------------------------------------
// LDS sizing for gg_big3 at worst-case s (compile-time)
// ---------------------------------------------------------------------------
template <int NK, int CHUNK, int LBLK, int SMAX>
constexpr int gg_lds_floats() {
  int o = 0;
  for (int cc = 0; cc < CHUNK; ++cc)
    for (int i = 0; i < NK; ++i) {
      int w = LBLK + 2 * (1 << (SMAX + i));
      o += (w + 3) & ~3;
    }
  return o;
}

// ---------------------------------------------------------------------------
// gg_big3: K-split, pipelined GConvGG for the large stages.
// 256 thr = 4 waves; wave -> 8 consecutive co (scalar weights); lane -> LPT
// CONSECUTIVE l's (wide b128/b64 LDS reads). Adaptive per-row staging widths
// (LBLK+2*dd) with runtime LDS offsets. Register-prefetch pipeline. Each
// block accumulates a ci-subrange into Y via fp32 atomicAdd (Y pre-zeroed).
// grid.x = lChunks * coChunks * 2 (K-split halves).
// ---------------------------------------------------------------------------
template <int NK, int CHUNK, int LPT, int MAXD, int SMAX>
__global__ __launch_bounds__(256) void gg_big3_kernel(
    const float* __restrict__ X, const float* __restrict__ W,
    const float* __restrict__ stIn, const float* __restrict__ gIn,
    const float* __restrict__ bIn, float invNIn, float* __restrict__ Y,
    int Ci, int Co, int Hin, int L, int lChunks, int coChunks, int splitChunk,
    int nChunksTot) {
  constexpr int LBLK = 64 * LPT;
  constexpr int ROWS = CHUNK * NK;
  constexpr int REPS = (LBLK + 2 * MAXD + 255) / 256;
  constexpr int LDSF = gg_lds_floats<NK, CHUNK, LBLK, SMAX>();

  const int bx = blockIdx.x;
  const int lc = bx % lChunks;
  const int t2 = bx / lChunks;
  const int cochunk = t2 % coChunks;
  const int ks = t2 / coChunks;
  const int s = blockIdx.y;
  const int b = blockIdx.z;
  const int Hout = Hin - NK + 1;
  const int l0 = lc * LBLK;
  const int tid = threadIdx.x;
  const int lane = tid & 63;
  const int wv = __builtin_amdgcn_readfirstlane(tid >> 6);
  const int coBase = cochunk * 32 + wv * 8;
  const int lb = lane * LPT;

  __shared__ float lds[LDSF];
  __shared__ float insc[416], inbi[416];

  for (int c = tid; c < Ci; c += 256) {
    float sc = 1.f, bi = 0.f;
    if (stIn) {
      float m = stIn[c] * invNIn;
      float v = stIn[512 + c] * invNIn - m * m;
      sc = gIn[c] * rsqrtf(v + EPSBN);
      bi = bIn[c] - m * sc;
    }
    insc[c] = sc;
    inbi[c] = bi;
  }
  __syncthreads();

  // runtime per-row LDS offsets (s-dependent adaptive widths), scalar math
  int offs[ROWS];
  {
    int o = 0;
#pragma unroll
    for (int r = 0; r < ROWS; ++r) {
      const int i = r % NK;
      int w = LBLK + 2 * (1 << (s + i));
      w = (w + 3) & ~3;
      offs[r] = o;
      o += w;
    }
  }

  float pre[ROWS][REPS];

  auto loadChunk = [&](int cIdx) {
#pragma unroll
    for (int r = 0; r < ROWS; ++r) {
      const int i = r % NK;
      const int ci = cIdx * CHUNK + r / NK;
      const int dd = 1 << (s + i);
      const int w = LBLK + 2 * dd;
      const float* src = X + (((size_t)b * Ci + ci) * Hin + (s + i)) * L;
#pragma unroll
      for (int rep = 0; rep < REPS; ++rep) {
        const int p = tid + rep * 256;
        if (p < w) {
          int pos = min(max(l0 - dd + p, 0), L - 1);
          pre[r][rep] = src[pos];
        }
      }
    }
  };

  auto writeChunk = [&](int cIdx) {
#pragma unroll
    for (int r = 0; r < ROWS; ++r) {
      const int i = r % NK;
      const int ci = cIdx * CHUNK + r / NK;
      const int dd = 1 << (s + i);
      const int w = LBLK + 2 * dd;
      const float inv = __uint_as_float((unsigned)(127 - (s + i)) << 23);
      const float sc = insc[ci], bi = inbi[ci];
      const bool edge = (l0 < dd) || (l0 + LBLK + dd > L);
#pragma unroll
      for (int rep = 0; rep < REPS; ++rep) {
        const int p = tid + rep * 256;
        if (p < w) {
          float a = fmaxf(fmaf(pre[r][rep], sc, bi), 0.f) * inv;
          if (edge) {
            int pos = l0 - dd + p;
            if (pos < 0 || pos >= L) a = 0.f;
          }
          lds[offs[r] + p] = a;
        }
      }
    }
  };

  float acc[8][LPT];
#pragma unroll
  for (int r = 0; r < 8; ++r)
#pragma unroll
    for (int j = 0; j < LPT; ++j) acc[r][j] = 0.f;

  const int cBeg = ks * splitChunk;
  const int cEnd = min(nChunksTot, cBeg + splitChunk);

  loadChunk(cBeg);
  for (int c0 = cBeg; c0 < cEnd; ++c0) {
    writeChunk(c0);
    if (c0 + 1 < cEnd) loadChunk(c0 + 1);
    __syncthreads();
    for (int cc = 0; cc < CHUNK; ++cc) {
      const int ci = c0 * CHUNK + cc;
#pragma unroll
      for (int i = 0; i < NK; ++i) {
        const int dd = 1 << (s + i);
        const float* row = lds + offs[cc * NK + i] + lb;
        float x0[LPT], x1[LPT], x2[LPT];
#pragma unroll
        for (int j = 0; j < LPT; ++j) {
          x0[j] = row[j];
          x1[j] = row[dd + j];
          x2[j] = row[2 * dd + j];
        }
#pragma unroll
        for (int r = 0; r < 8; ++r) {
          const int co = min(coBase + r, Co - 1);
          const float* w3 = W + (((size_t)co * Ci + ci) * NK + i) * 3;
          const float w0 = w3[0], w1 = w3[1], w2 = w3[2];
#pragma unroll
          for (int j = 0; j < LPT; ++j)
            acc[r][j] =
                fmaf(w0, x0[j], fmaf(w1, x1[j], fmaf(w2, x2[j], acc[r][j])));
        }
      }
    }
    __syncthreads();
  }

#pragma unroll
  for (int r = 0; r < 8; ++r) {
    const int co = coBase + r;
    if (co < Co) {
      float* yp = Y + (((size_t)b * Co + co) * Hout + s) * L + l0 + lb;
#pragma unroll
      for (int j = 0; j < LPT; ++j) atomicAdd(&yp[j], acc[r][j]);
    }
  }
}

// ---------------------------------------------------------------------------
// gg_tail: no-LDS GConvGG for small stages (input pre-activated)
// ---------------------------------------------------------------------------
template <int NK, int L, int COSUB>
__global__ __launch_bounds__(256) void gg_tail_kernel(
    const float* __restrict__ X, const float* __restrict__ W,
    float* __restrict__ Y, float* __restrict__ stOut, int Ci, int Co,
    int Hin) {
  const int l = threadIdx.x % L;
  const int cs = threadIdx.x / L;
  const int co = blockIdx.x * COSUB + cs;
  const int s = blockIdx.y;
  const int b = blockIdx.z;
  const int Hout = Hin - NK + 1;

  float acc[NK];
#pragma unroll
  for (int i = 0; i < NK; ++i) acc[i] = 0.f;

  const float* wbase = W + (size_t)co * Ci * NK * 3;
  const float* xbase = X + ((size_t)b * Ci * Hin + s) * L;

  for (int ci = 0; ci < Ci; ++ci) {
    const float* wp = wbase + ci * (NK * 3);
    const float* xr = xbase + ci * (Hin * L);
#pragma unroll
    for (int i = 0; i < NK; ++i) {
      const int d = 1 << (s + i);
      const float* row = xr + i * L;
      float xm = (l >= d) ? row[l - d] : 0.f;
      float xc = row[l];
      float xp = (l + d < L) ? row[l + d] : 0.f;
      acc[i] = fmaf(wp[3 * i], xm,
                    fmaf(wp[3 * i + 1], xc, fmaf(wp[3 * i + 2], xp, acc[i])));
    }
  }
  float out = 0.f;
#pragma unroll
  for (int i = 0; i < NK; ++i) {
    float invd = __uint_as_float((unsigned)(127 - (s + i)) << 23);
    out = fmaf(acc[i], invd, out);
  }
  Y[(((size_t)b * Co + co) * Hout + s) * L + l] = out;

  float s1 = out, s2 = out * out;
  constexpr int RED = (L < 64) ? L : 64;
#pragma unroll
  for (int off = RED / 2; off > 0; off >>= 1) {
    s1 += __shfl_xor(s1, off);
    s2 += __shfl_xor(s2, off);
  }
  if ((threadIdx.x & (RED - 1)) == 0) {
    atomicAdd(&stOut[co], s1);
    atomicAdd(&stOut[512 + co], s2);
  }
}

// ---------------------------------------------------------------------------
// Final: bn10+relu, mean over L, classifier
// ---------------------------------------------------------------------------
__global__ __launch_bounds__(256) void final_kernel(
    const float* __restrict__ Y, const float* __restrict__ st,
    const float* __restrict__ g, const float* __restrict__ bb,
    const float* __restrict__ w11, float* __restrict__ out) {
  const int b = blockIdx.x;
  const int tid = threadIdx.x;
  __shared__ float tch[408];
  for (int c = tid; c < 408; c += 256) {
    float m = st[c] * (1.f / 256.f);
    float v = st[512 + c] * (1.f / 256.f) - m * m;
    float sc = g[c] * rsqrtf(v + EPSBN);
    float bi = bb[c] - m * sc;
    const float* p = Y + ((size_t)b * 408 + c) * 32;
    float ssum = 0.f;
#pragma unroll
    for (int l = 0; l < 32; ++l) ssum += fmaxf(p[l] * sc + bi, 0.f);
    tch[c] = ssum * (1.f / 32.f);
  }
  __syncthreads();
  if (tid < 10) {
    float ssum = 0.f;
    for (int c = 0; c < 408; ++c) ssum += w11[tid * 408 + c] * tch[c];
    out[b * 10 + tid] = ssum;
  }
}

// ---------------------------------------------------------------------------
extern "C" void kernel_launch(void* const* d_in, const int* in_sizes, int n_in,
                              void* d_out, int out_size, void* d_ws,
                              size_t ws_size, hipStream_t stream) {
  const float* x = (const float*)d_in[0];
  const float* w1 = (const float*)d_in[1];
  const float* w2 = (const float*)d_in[2];
  const float* w3 = (const float*)d_in[3];
  const float* w4 = (const float*)d_in[4];
  const float* w5 = (const float*)d_in[5];
  const float* w6 = (const float*)d_in[6];
  const float* w7 = (const float*)d_in[7];
  const float* w8 = (const float*)d_in[8];
  const float* w9 = (const float*)d_in[9];
  const float* w10 = (const float*)d_in[10];
  const float* w11 = (const float*)d_in[11];
  const float* gg[11];
  const float* bbv[11];
  for (int i = 1; i <= 10; ++i) {
    gg[i] = (const float*)d_in[12 + 2 * (i - 1)];
    bbv[i] = (const float*)d_in[12 + 2 * (i - 1) + 1];
  }

  float* ws = (float*)d_ws;
  const size_t AR0 = 0;
  const size_t AR1 = 30081024;
  const size_t STATS = 37601280;
  float* y1 = ws + AR0;
  float* xpad = ws + AR1;
  float* z1 = ws + AR1;
  float* y2 = ws + AR0;
  float* y3 = ws + AR0 + 5849088;
  float* z3 = ws + AR1;
  float* y4 = ws + AR0;
  float* y5 = ws + AR0 + 2088960;
  float* z5 = ws + AR1;
  float* a6 = ws + AR1 + 522240;
  float* a7 = ws + AR1 + 1148928;
  float* z8 = ws + AR1;
  float* a9 = ws + AR1 + 1775616;
  float* y6 = ws + AR0;
  float* y7 = ws + AR0 + 626688;
  float* y8 = ws + AR0 + 1253376;
  float* y9 = ws + AR0;
  float* y10 = ws + AR0 + 104448;
  float* st[11];
  for (int i = 1; i <= 10; ++i) st[i] = ws + STATS + (size_t)(i - 1) * 1024;

  hipMemsetAsync((void*)(ws + STATS), 0, 10 * 1024 * sizeof(float), stream);

  // ---- pad + lift (stats1 fused)
  pad_x_kernel<<<(8 * PROW + 255) / 256, 256, 0, stream>>>(x, xpad);
  {
    dim3 g(8, 51, 8);
    lift_pool2_kernel<0><<<g, 256, 0, stream>>>(xpad, w1, y1, st[1]);
    lift_pool2_kernel<1><<<g, 256, 0, stream>>>(xpad, w1, y1, st[1]);
    lift_pool2_kernel<2><<<g, 256, 0, stream>>>(xpad, w1, y1, st[1]);
    lift_pool2_kernel<3><<<g, 256, 0, stream>>>(xpad, w1, y1, st[1]);
    lift_pool2_kernel<4><<<g, 256, 0, stream>>>(xpad, w1, y1, st[1]);
    lift_pool2_kernel<5><<<g, 256, 0, stream>>>(xpad, w1, y1, st[1]);
    lift_pool2_kernel<6><<<g, 256, 0, stream>>>(xpad, w1, y1, st[1]);
    lift_pool2_kernel<7><<<g, 256, 0, stream>>>(xpad, w1, y1, st[1]);
    lift_pool2_kernel<8><<<g, 256, 0, stream>>>(xpad, w1, y1, st[1]);
  }
  {
    unsigned int tot = 8u * 51 * 9 * 2048;
    bnrelu_pool_kernel<<<(tot + 255) / 256, 256, 0, stream>>>(
        y1, st[1], gg[1], bbv[1], z1, 51, 9, 8192, 1.f / 589824.f, tot);
  }
  // ---- gg2: 51->51, H 9->7, L=2048.  K-split 27/24 ci, atomic accumulate.
  hipMemsetAsync((void*)y2, 0, 5849088 * sizeof(float), stream);
  gg_big3_kernel<3, 3, 4, 256, 6><<<dim3(32, 7, 8), 256, 0, stream>>>(
      z1, w2, nullptr, nullptr, nullptr, 0.f, y2, 51, 51, 9, 2048, 8, 2, 9,
      17);
  stats_kernel<<<dim3(51, 8), 256, 0, stream>>>(y2, st[2], 51, 7 * 2048);
  // ---- gg3: 51->51, H7, L=2048 (bn2 on load)
  hipMemsetAsync((void*)y3, 0, 5849088 * sizeof(float), stream);
  gg_big3_kernel<1, 3, 4, 64, 6><<<dim3(32, 7, 8), 256, 0, stream>>>(
      y2, w3, st[2], gg[2], bbv[2], 1.f / 114688.f, y3, 51, 51, 7, 2048, 8, 2,
      9, 17);
  stats_kernel<<<dim3(51, 8), 256, 0, stream>>>(y3, st[3], 51, 7 * 2048);
  {
    unsigned int tot = 8u * 51 * 7 * 512;
    bnrelu_pool_kernel<<<(tot + 255) / 256, 256, 0, stream>>>(
        y3, st[3], gg[3], bbv[3], z3, 51, 7, 2048, 1.f / 114688.f, tot);
  }
  // ---- gg4: 51->102, H 7->5, L=512
  hipMemsetAsync((void*)y4, 0, 2088960 * sizeof(float), stream);
  gg_big3_kernel<3, 3, 2, 64, 4><<<dim3(32, 5, 8), 256, 0, stream>>>(
      z3, w4, nullptr, nullptr, nullptr, 0.f, y4, 51, 102, 7, 512, 4, 4, 9,
      17);
  stats_kernel<<<dim3(102, 8), 256, 0, stream>>>(y4, st[4], 102, 5 * 512);
  // ---- gg5: 102->102, H5, L=512
  hipMemsetAsync((void*)y5, 0, 2088960 * sizeof(float), stream);
  gg_big3_kernel<1, 3, 2, 16, 4><<<dim3(32, 5, 8), 256, 0, stream>>>(
      y4, w5, st[4], gg[4], bbv[4], 1.f / 20480.f, y5, 102, 102, 5, 512, 4, 4,
      17, 34);
  stats_kernel<<<dim3(102, 8), 256, 0, stream>>>(y5, st[5], 102, 5 * 512);
  {
    unsigned int tot = 8u * 102 * 5 * 128;
    bnrelu_pool_kernel<<<(tot + 255) / 256, 256, 0, stream>>>(
        y5, st[5], gg[5], bbv[5], z5, 102, 5, 512, 1.f / 20480.f, tot);
  }
  // ---- gg6: 102->204, H 5->3, L=128
  gg_tail_kernel<3, 128, 2><<<dim3(102, 3, 8), 256, 0, stream>>>(
      z5, w6, y6, st[6], 102, 204, 5);
  {
    unsigned int tot = 8u * 204 * 3 * 128;
    bnrelu_kernel<<<(tot + 255) / 256, 256, 0, stream>>>(
        y6, st[6], gg[6], bbv[6], a6, 204, 3 * 128, 1.f / 3072.f, tot);
  }
  // ---- gg7: 204->204, H3, L=128
  gg_tail_kernel<1, 128, 2><<<dim3(102, 3, 8), 256, 0, stream>>>(
      a6, w7, y7, st[7], 204, 204, 3);
  {
    unsigned int tot = 8u * 204 * 3 * 128;
    bnrelu_kernel<<<(tot + 255) / 256, 256, 0, stream>>>(
        y7, st[7], gg[7], bbv[7], a7, 204, 3 * 128, 1.f / 3072.f, tot);
  }
  // ---- gg8: 204->204, H3, L=128
  gg_tail_kernel<1, 128, 2><<<dim3(102, 3, 8), 256, 0, stream>>>(
      a7, w8, y8, st[8], 204, 204, 3);
  {
    unsigned int tot = 8u * 204 * 3 * 32;
    bnrelu_pool_kernel<<<(tot + 255) / 256, 256, 0, stream>>>(
        y8, st[8], gg[8], bbv[8], z8, 204, 3, 128, 1.f / 3072.f, tot);
  }
  // ---- gg9: 204->408, H 3->1, L=32
  gg_tail_kernel<3, 32, 8><<<dim3(51, 1, 8), 256, 0, stream>>>(
      z8, w9, y9, st[9], 204, 408, 3);
  {
    unsigned int tot = 8u * 408 * 32;
    bnrelu_kernel<<<(tot + 255) / 256, 256, 0, stream>>>(
        y9, st[9], gg[9], bbv[9], a9, 408, 32, 1.f / 256.f, tot);
  }
  // ---- gg10: 408->408, H1, L=32
  gg_tail_kernel<1, 32, 8><<<dim3(51, 1, 8), 256, 0, stream>>>(
      a9, w10, y10, st[10], 408, 408, 1);
  // ---- final
  final_kernel<<<dim3(8), 256, 0, stream>>>(y10, st[10], gg[10], bbv[10], w11,
                                            (float*)d_out);
}